// Round 11
// baseline (68.945 us; speedup 1.0000x reference)
//
#include <hip/hip_runtime.h>
#include <hip/hip_bf16.h>

// Problem constants
#define L_SEQ   4096
#define D_IN    1024
#define N_BATCH 16
#define L_OUT   1024
#define D_OUT   1024
#define M_DIM   (N_BATCH * L_OUT)   // 16384
#define K_DIM   D_IN

// GEMM tiling (256x256 8-phase template)
#define BM 256
#define BN 256
#define BK 64
#define NKT (K_DIM / BK)   // 16

typedef __attribute__((ext_vector_type(4))) float  f32x4;
typedef __attribute__((ext_vector_type(8))) __bf16 bf16x8;
typedef __attribute__((ext_vector_type(4))) __bf16 bf16x4;

// ws layout (bytes)
#define WS_A_OFF 0u
#define WS_W_OFF (32u * 1024u * 1024u)
#define WS_S_OFF (WS_W_OFF + 2u * 1024u * 1024u)

// ---------------------------------------------------------------------------
// Kernel 1 (prep): blocks 0..15 -> mask sums; blocks 16..1039 -> W rows
// W rows bf16, pre-swizzled: elem e -> (e&~63) | ((e&63) ^ ((row&7)<<3)).
// ---------------------------------------------------------------------------
__global__ __launch_bounds__(256) void prep_kernel(
    const int*   __restrict__ mask,  // (16, 4096)
    const float* __restrict__ W,     // (1024, 1024)
    int*    __restrict__ s_out,      // (16,)
    __bf16* __restrict__ wsW)        // (1024, 1024) swizzled
{
    const int t = threadIdx.x;
    if (blockIdx.x < 16) {
        const int b = blockIdx.x;
        const int* row = mask + (size_t)b * L_SEQ;
        int sum = 0;
#pragma unroll
        for (int i = 0; i < L_SEQ / 256; ++i) sum += row[t + i * 256];
#pragma unroll
        for (int off = 32; off > 0; off >>= 1) sum += __shfl_down(sum, off, 64);
        __shared__ int wsum[4];
        if ((t & 63) == 0) wsum[t >> 6] = sum;
        __syncthreads();
        if (t == 0) {
            int total = wsum[0] + wsum[1] + wsum[2] + wsum[3];
            s_out[b] = total < L_OUT ? total : L_OUT;
        }
    } else {
        const int n  = blockIdx.x - 16;          // 0..1023
        const int e0 = t * 4;
        const int rsw  = (n & 7) << 3;
        const int dste = (e0 & ~63) | ((e0 & 63) ^ rsw);
        const float* src = W + (size_t)n * D_IN + e0;
        f32x4 v = *(const f32x4*)src;
        bf16x4 o = {(__bf16)v.x, (__bf16)v.y, (__bf16)v.z, (__bf16)v.w};
        *(bf16x4*)(wsW + (size_t)n * K_DIM + dste) = o;
    }
}

// ---------------------------------------------------------------------------
// Kernel 2: GEMM with in-kernel idempotent A-panel convert.
//   pre-pass: each block converts its own A panel (256 rows x 1024 K) from
//   fp32 x (restrict+zero-pad+cast+swizzle) into wsA. The 4 blocks sharing a
//   panel (tile_n=0..3, same XCD via T1 swizzle) write IDENTICAL bytes ->
//   benign duplication, L2 MSHR-merges reads and absorbs duplicate writes.
//   Each block reads back only its own writes: stores -> vmcnt(0) -> barrier
//   -> global_load_lds through the same L2. No cross-block dependency.
// K-loop/ledger/epilogue byte-identical to the R8 checkpoint:
//   at kt's P1 the 4 newest outstanding are kt-1:P3,P4 -> vmcnt(4) exact.
// ---------------------------------------------------------------------------
__device__ __forceinline__ void gload16(const __bf16* g, __bf16* l) {
    __builtin_amdgcn_global_load_lds(
        (const __attribute__((address_space(1))) void*)g,
        (__attribute__((address_space(3))) void*)l,
        16, 0, 0);
}

#define FENCE() asm volatile("" ::: "memory")

__global__ __launch_bounds__(512, 2) void gemm_kernel(
    const float*  __restrict__ x,    // (16, 4096, 1024) fp32
    const __bf16* __restrict__ Wb,   // (1024, 1024) swizzled bf16 (ws)
    const float*  __restrict__ bias, // (1024,)
    const int*    __restrict__ s_arr,// (16,)
    __bf16*       __restrict__ wsA,  // (16384, 1024) swizzled bf16 (ws)
    float* __restrict__ out)         // (16384, 1024)
{
    __shared__ __bf16 smem[2][2][BM * BK];   // 128 KiB

    const int t  = threadIdx.x;       // 0..511
    const int bx = blockIdx.x;        // 256 blocks
    const int vb = (bx & 7) * 32 + (bx >> 3);  // T1 XCD-grouping swizzle
    const int tile_n = vb & 3;        // N/BN = 4
    const int tile_m = vb >> 2;       // M/BM = 64
    const int m0 = tile_m * BM;
    const int n0 = tile_n * BN;
    const int lane = t & 63;
    const int wave = t >> 6;
    const int wm = wave >> 2;         // 0..1
    const int wn = wave & 3;          // 0..3

    // ================= pre-pass: convert own A panel =================
    {
        const int bb = m0 >> 10;                 // batch
        const int s  = s_arr[bb];
        const int jb = m0 & (L_OUT - 1);         // panel row offset in batch
        const float* xb = x + ((size_t)bb * L_SEQ + (size_t)(L_SEQ - s)) * D_IN;
        __bf16* wA = wsA + (size_t)m0 * K_DIM;
        const int rset = t >> 7;                 // 0..3
        const int cg   = (t & 127) * 8;          // elem col group (8-aligned)
        const bf16x8 zo = {(__bf16)0.f, (__bf16)0.f, (__bf16)0.f, (__bf16)0.f,
                           (__bf16)0.f, (__bf16)0.f, (__bf16)0.f, (__bf16)0.f};
#pragma unroll 4
        for (int sw = 0; sw < 64; ++sw) {
            const int r = rset + sw * 4;         // 0..255 (wave-uniform)
            const int j = jb + r;
            const int dste = (cg & ~63) | ((cg & 63) ^ ((r & 7) << 3));
            __bf16* dst = wA + (size_t)r * K_DIM + dste;
            if (j < s) {
                const float* src = xb + (size_t)j * D_IN + cg;
                f32x4 v0 = *(const f32x4*)(src);
                f32x4 v1 = *(const f32x4*)(src + 4);
                bf16x8 o = {(__bf16)v0.x, (__bf16)v0.y, (__bf16)v0.z, (__bf16)v0.w,
                            (__bf16)v1.x, (__bf16)v1.y, (__bf16)v1.z, (__bf16)v1.w};
                *(bf16x8*)dst = o;
            } else {
                *(bf16x8*)dst = zo;
            }
        }
        // own writes must be retired to L2 before global_load_lds reads them
        asm volatile("s_waitcnt vmcnt(0)" ::: "memory");
        __builtin_amdgcn_s_barrier();
    }

    // ================= GEMM (R8 structure, unchanged) =================
    const int srow = t >> 3;          // 0..63
    const int scol = (t & 7) * 8;     // linear source elem col

    const __bf16* Ag = wsA + (size_t)m0 * K_DIM;
    const __bf16* Bg = Wb  + (size_t)n0 * K_DIM;

#define STAGE_HALF(gbase, lbase, h, kt_)                                   \
    {                                                                      \
        _Pragma("unroll")                                                  \
        for (int rd = 0; rd < 2; ++rd) {                                   \
            const int r_ = (h) * 128 + rd * 64 + srow;                     \
            gload16((gbase) + (size_t)r_ * K_DIM + (kt_) * BK + scol,      \
                    (lbase) + r_ * BK + scol);                             \
        }                                                                  \
    }

    // fragment read geometry
    const int fr  = lane & 15;
    const int k8  = (lane >> 4) * 8;
    const int swz = (fr & 7) << 3;
    const int kc0 = k8 ^ swz;
    const int kc1 = (32 + k8) ^ swz;

    // bias hoisted ahead of the K-loop
    float bias_v[4];
#pragma unroll
    for (int g = 0; g < 4; ++g)
        bias_v[g] = bias[n0 + wn * 64 + g * 16 + fr];

    bf16x8 aF[4][2], bF0[2][2], bF1[2][2];
    f32x4 acc[8][4];
#pragma unroll
    for (int f = 0; f < 8; ++f)
#pragma unroll
        for (int g = 0; g < 4; ++g) acc[f][g] = (f32x4){0.f, 0.f, 0.f, 0.f};

#define LOAD_AF(Ac, mh)                                                    \
    {                                                                      \
        const __bf16* rb_ = (Ac) + (wm * 128 + (mh) * 64 + fr) * BK;       \
        _Pragma("unroll")                                                  \
        for (int i = 0; i < 4; ++i) {                                      \
            aF[i][0] = *(const bf16x8*)&rb_[i * 16 * BK + kc0];            \
            aF[i][1] = *(const bf16x8*)&rb_[i * 16 * BK + kc1];            \
        }                                                                  \
    }

#define LOAD_BF(Bc, nh, bF)                                                \
    {                                                                      \
        const __bf16* rb_ = (Bc) + (wn * 64 + (nh) * 32 + fr) * BK;        \
        _Pragma("unroll")                                                  \
        for (int j = 0; j < 2; ++j) {                                      \
            bF[j][0] = *(const bf16x8*)&rb_[j * 16 * BK + kc0];            \
            bF[j][1] = *(const bf16x8*)&rb_[j * 16 * BK + kc1];            \
        }                                                                  \
    }

#define MFMA_QUAD(mh, nh, bF)                                              \
    {                                                                      \
        _Pragma("unroll")                                                  \
        for (int i = 0; i < 4; ++i)                                        \
            _Pragma("unroll")                                              \
            for (int j = 0; j < 2; ++j) {                                  \
                f32x4 c_ = acc[(mh) * 4 + i][(nh) * 2 + j];                \
                c_ = __builtin_amdgcn_mfma_f32_16x16x32_bf16(              \
                    aF[i][0], bF[j][0], c_, 0, 0, 0);                      \
                c_ = __builtin_amdgcn_mfma_f32_16x16x32_bf16(              \
                    aF[i][1], bF[j][1], c_, 0, 0, 0);                      \
                acc[(mh) * 4 + i][(nh) * 2 + j] = c_;                      \
            }                                                              \
    }

    // prologue: loads 1-8 = full buf0(kt=0); 9-12 = A(1)h0, B(1)h1.
    {
        __bf16* A0l = &smem[0][0][0];
        __bf16* B0l = &smem[0][1][0];
        __bf16* A1l = &smem[1][0][0];
        __bf16* B1l = &smem[1][1][0];
        STAGE_HALF(Ag, A0l, 0, 0);
        STAGE_HALF(Bg, B0l, 1, 0);
        STAGE_HALF(Ag, A0l, 1, 0);
        STAGE_HALF(Bg, B0l, 0, 0);
        STAGE_HALF(Ag, A1l, 0, 1);
        STAGE_HALF(Bg, B1l, 1, 1);
    }

    for (int kt = 0; kt < NKT; ++kt) {
        const int cur = kt & 1;
        __bf16* Ac = &smem[cur][0][0];
        __bf16* Bc = &smem[cur][1][0];
        __bf16* An = &smem[cur ^ 1][0][0];
        __bf16* Bn = &smem[cur ^ 1][1][0];

        // ---- P1: quadrant (0,0) ----
        FENCE();
        if (kt == NKT - 1) asm volatile("s_waitcnt vmcnt(0)" ::: "memory");
        else               asm volatile("s_waitcnt vmcnt(4)" ::: "memory");
        __builtin_amdgcn_s_barrier();
        FENCE();
        LOAD_AF(Ac, 0);
        LOAD_BF(Bc, 0, bF0);
        if (kt + 1 < NKT) {
            STAGE_HALF(Ag, An, 1, kt + 1);
            STAGE_HALF(Bg, Bn, 0, kt + 1);
        }
        asm volatile("s_waitcnt lgkmcnt(0)" ::: "memory");
        __builtin_amdgcn_sched_barrier(0);
        __builtin_amdgcn_s_setprio(1);
        MFMA_QUAD(0, 0, bF0);
        __builtin_amdgcn_s_setprio(0);

        // ---- P2: quadrant (0,1) ----
        FENCE();
        __builtin_amdgcn_s_barrier();
        FENCE();
        LOAD_BF(Bc, 1, bF1);
        asm volatile("s_waitcnt lgkmcnt(0)" ::: "memory");
        __builtin_amdgcn_sched_barrier(0);
        __builtin_amdgcn_s_setprio(1);
        MFMA_QUAD(0, 1, bF1);
        __builtin_amdgcn_s_setprio(0);

        // ---- P3: quadrant (1,1) ----
        FENCE();
        __builtin_amdgcn_s_barrier();
        FENCE();
        LOAD_AF(Ac, 1);
        if (kt + 2 < NKT) STAGE_HALF(Ag, Ac, 0, kt + 2);
        asm volatile("s_waitcnt lgkmcnt(0)" ::: "memory");
        __builtin_amdgcn_sched_barrier(0);
        __builtin_amdgcn_s_setprio(1);
        MFMA_QUAD(1, 1, bF1);
        __builtin_amdgcn_s_setprio(0);

        // ---- P4: quadrant (1,0) ----
        FENCE();
        __builtin_amdgcn_s_barrier();
        FENCE();
        if (kt + 2 < NKT) STAGE_HALF(Bg, Bc, 1, kt + 2);
        __builtin_amdgcn_s_setprio(1);
        MFMA_QUAD(1, 0, bF0);
        __builtin_amdgcn_s_setprio(0);
    }

    // epilogue: bias + store
    const int row0 = m0 + wm * 128 + (lane >> 4) * 4;
    const int col0 = n0 + wn * 64 + fr;
#pragma unroll
    for (int f = 0; f < 8; ++f)
#pragma unroll
        for (int g = 0; g < 4; ++g)
#pragma unroll
            for (int rr = 0; rr < 4; ++rr)
                out[(size_t)(row0 + f * 16 + rr) * D_OUT + (col0 + g * 16)] =
                    acc[f][g][rr] + bias_v[g];

#undef STAGE_HALF
#undef LOAD_AF
#undef LOAD_BF
#undef MFMA_QUAD
}

// ---------------------------------------------------------------------------
extern "C" void kernel_launch(void* const* d_in, const int* in_sizes, int n_in,
                              void* d_out, int out_size, void* d_ws, size_t ws_size,
                              hipStream_t stream) {
    const float* x    = (const float*)d_in[0];
    const int*   mask = (const int*)d_in[1];
    const float* W    = (const float*)d_in[2];
    const float* bias = (const float*)d_in[3];
    float*       out  = (float*)d_out;

    __bf16* wsA   = (__bf16*)((char*)d_ws + WS_A_OFF);
    __bf16* wsW   = (__bf16*)((char*)d_ws + WS_W_OFF);
    int*    s_arr = (int*)((char*)d_ws + WS_S_OFF);

    prep_kernel<<<dim3(16 + D_OUT), dim3(256), 0, stream>>>(
        mask, W, s_arr, wsW);

    const int grid = (M_DIM / BM) * (D_OUT / BN);  // 64 * 4 = 256
    gemm_kernel<<<dim3(grid), dim3(512), 0, stream>>>(
        x, wsW, bias, s_arr, wsA, out);
}

// Round 12
// 64.896 us; speedup vs baseline: 1.0624x; 1.0624x over previous
//
#include <hip/hip_runtime.h>
#include <hip/hip_bf16.h>

// Problem constants
#define L_SEQ   4096
#define D_IN    1024
#define N_BATCH 16
#define L_OUT   1024
#define D_OUT   1024
#define M_DIM   (N_BATCH * L_OUT)   // 16384
#define K_DIM   D_IN

// GEMM tiling (256x256, 4-phase, 32x32x16 MFMA)
#define BM 256
#define BN 256
#define BK 64
#define NKT (K_DIM / BK)   // 16

typedef __attribute__((ext_vector_type(4)))  float  f32x4;
typedef __attribute__((ext_vector_type(16))) float  f32x16;
typedef __attribute__((ext_vector_type(8)))  __bf16 bf16x8;
typedef __attribute__((ext_vector_type(4)))  __bf16 bf16x4;

// ws layout (bytes)
#define WS_A_OFF 0u
#define WS_W_OFF (32u * 1024u * 1024u)
#define WS_S_OFF (WS_W_OFF + 2u * 1024u * 1024u)

// ---------------------------------------------------------------------------
// Kernel 1: s[b] = min(sum(attention_mask[b,:]), L_OUT)
// ---------------------------------------------------------------------------
__global__ __launch_bounds__(256) void mask_sum_kernel(
    const int* __restrict__ mask, int* __restrict__ s_out)
{
    const int b = blockIdx.x;
    const int t = threadIdx.x;
    const int* row = mask + (size_t)b * L_SEQ;

    int sum = 0;
#pragma unroll
    for (int i = 0; i < L_SEQ / 256; ++i) sum += row[t + i * 256];

#pragma unroll
    for (int off = 32; off > 0; off >>= 1) sum += __shfl_down(sum, off, 64);

    __shared__ int wsum[4];
    if ((t & 63) == 0) wsum[t >> 6] = sum;
    __syncthreads();
    if (t == 0) {
        int total = wsum[0] + wsum[1] + wsum[2] + wsum[3];
        s_out[b] = total < L_OUT ? total : L_OUT;
    }
}

// ---------------------------------------------------------------------------
// Kernel 2: build bf16 A (restricted+zero-padded) and bf16 W in ws,
// pre-swizzled per row: elem e -> (e & ~63) | ((e & 63) ^ ((row&7)<<3)).
// Producer-XCD alignment: A-block cb -> row rid = (cb&7)*2048 + (cb>>3).
// ---------------------------------------------------------------------------
__global__ __launch_bounds__(256) void convert_kernel(
    const float* __restrict__ x,     // (16, 4096, 1024)
    const float* __restrict__ W,     // (1024, 1024)
    const int*   __restrict__ s_arr, // (16,)
    __bf16* __restrict__ wsA,        // (16384, 1024)
    __bf16* __restrict__ wsW)        // (1024, 1024)
{
    const int cb = blockIdx.x;
    const int t  = threadIdx.x;
    const int e0 = t * 4;

    if (cb < M_DIM) {
        const int rid = (cb & 7) * 2048 + (cb >> 3);   // XCD-aligned remap
        const int b = rid >> 10;
        const int j = rid & (L_OUT - 1);
        const int s = s_arr[b];
        const int rsw  = (rid & 7) << 3;
        const int dste = (e0 & ~63) | ((e0 & 63) ^ rsw);
        __bf16* dst = wsA + (size_t)rid * K_DIM + dste;
        if (j < s) {
            const float* src = x + ((size_t)b * L_SEQ + (L_SEQ - s + j)) * D_IN + e0;
            f32x4 v = *(const f32x4*)src;
            bf16x4 o = {(__bf16)v.x, (__bf16)v.y, (__bf16)v.z, (__bf16)v.w};
            *(bf16x4*)dst = o;
        } else {
            bf16x4 o = {(__bf16)0.f, (__bf16)0.f, (__bf16)0.f, (__bf16)0.f};
            *(bf16x4*)dst = o;
        }
    } else {
        const int n = cb - M_DIM;
        const int rsw  = (n & 7) << 3;
        const int dste = (e0 & ~63) | ((e0 & 63) ^ rsw);
        const float* src = W + (size_t)n * D_IN + e0;
        f32x4 v = *(const f32x4*)src;
        bf16x4 o = {(__bf16)v.x, (__bf16)v.y, (__bf16)v.z, (__bf16)v.w};
        *(bf16x4*)(wsW + (size_t)n * K_DIM + dste) = o;
    }
}

// ---------------------------------------------------------------------------
// Kernel 3: 256x256 GEMM, 4 barrier-phases/K-tile, counted vmcnt,
// 32x32x16 bf16 MFMA (2495 TF ceiling vs 2176 for 16x16x32; same LDS bytes).
// Wave tile 128x64 = 4 mt x 2 nt of 32x32; acc[4][2] f32x16 (128 VGPR).
// A-frag: row=lane&31, k=(lane>>5)*8+e (generalizes verified 16x16 layout).
// C/D:    col=lane&31, row=(r&3)+8*(r>>2)+4*(lane>>5)  [HW-verified m74/m101].
// Staging/barriers/vmcnt ledger byte-identical to R8:
//   at kt's P1 the 4 newest outstanding are kt-1:P3,P4 -> vmcnt(4) exact.
// ---------------------------------------------------------------------------
__device__ __forceinline__ void gload16(const __bf16* g, __bf16* l) {
    __builtin_amdgcn_global_load_lds(
        (const __attribute__((address_space(1))) void*)g,
        (__attribute__((address_space(3))) void*)l,
        16, 0, 0);
}

#define FENCE() asm volatile("" ::: "memory")

__global__ __launch_bounds__(512, 2) void gemm_kernel(
    const __bf16* __restrict__ A,    // (16384, 1024) swizzled rows
    const __bf16* __restrict__ Wb,   // (1024, 1024)  swizzled rows
    const float*  __restrict__ bias, // (1024,)
    float* __restrict__ out)         // (16384, 1024)
{
    __shared__ __bf16 smem[2][2][BM * BK];   // 128 KiB

    const int t  = threadIdx.x;       // 0..511
    const int bx = blockIdx.x;        // 256 blocks
    const int vb = (bx & 7) * 32 + (bx >> 3);  // XCD-grouping swizzle
    const int tile_n = vb & 3;        // N/BN = 4
    const int tile_m = vb >> 2;       // M/BM = 64
    const int m0 = tile_m * BM;
    const int n0 = tile_n * BN;
    const int lane = t & 63;
    const int wave = t >> 6;
    const int wm = wave >> 2;         // 0..1
    const int wn = wave & 3;          // 0..3

    const int srow = t >> 3;          // 0..63
    const int scol = (t & 7) * 8;     // linear source elem col

    const __bf16* Ag = A  + (size_t)m0 * K_DIM;
    const __bf16* Bg = Wb + (size_t)n0 * K_DIM;

#define STAGE_HALF(gbase, lbase, h, kt_)                                   \
    {                                                                      \
        _Pragma("unroll")                                                  \
        for (int rd = 0; rd < 2; ++rd) {                                   \
            const int r_ = (h) * 128 + rd * 64 + srow;                     \
            gload16((gbase) + (size_t)r_ * K_DIM + (kt_) * BK + scol,      \
                    (lbase) + r_ * BK + scol);                             \
        }                                                                  \
    }

    // fragment read geometry (32x32x16): row=lane&31, k=(lane>>5)*8 + sk*16
    const int r32 = lane & 31;
    const int k8b = (lane >> 5) * 8;
    const int swz = (r32 & 7) << 3;
    int kc32[4];
#pragma unroll
    for (int sk = 0; sk < 4; ++sk) kc32[sk] = (sk * 16 + k8b) ^ swz;

    // bias (2 values/lane) hoisted ahead of the K-loop
    const int col0 = n0 + wn * 64 + r32;
    float bias_v[2];
#pragma unroll
    for (int nt = 0; nt < 2; ++nt) bias_v[nt] = bias[col0 + nt * 32];

    bf16x8 aF[2][4], bF0[4], bF1[4];
    f32x16 acc[4][2];
#pragma unroll
    for (int mt = 0; mt < 4; ++mt)
#pragma unroll
        for (int nt = 0; nt < 2; ++nt)
#pragma unroll
            for (int r = 0; r < 16; ++r) acc[mt][nt][r] = 0.f;

#define LOAD_AF(Ac, mh)                                                    \
    {                                                                      \
        _Pragma("unroll")                                                  \
        for (int mt2 = 0; mt2 < 2; ++mt2) {                                \
            const __bf16* rb_ =                                            \
                (Ac) + (wm * 128 + (mh) * 64 + mt2 * 32 + r32) * BK;       \
            _Pragma("unroll")                                              \
            for (int sk = 0; sk < 4; ++sk)                                 \
                aF[mt2][sk] = *(const bf16x8*)&rb_[kc32[sk]];              \
        }                                                                  \
    }

#define LOAD_BF(Bc, nh, BF)                                                \
    {                                                                      \
        const __bf16* rb_ = (Bc) + (wn * 64 + (nh) * 32 + r32) * BK;       \
        _Pragma("unroll")                                                  \
        for (int sk = 0; sk < 4; ++sk)                                     \
            BF[sk] = *(const bf16x8*)&rb_[kc32[sk]];                       \
    }

#define MFMA_QUAD(mh, nh, BF)                                              \
    {                                                                      \
        _Pragma("unroll")                                                  \
        for (int mt2 = 0; mt2 < 2; ++mt2) {                                \
            f32x16 c_ = acc[(mh) * 2 + mt2][nh];                           \
            _Pragma("unroll")                                              \
            for (int sk = 0; sk < 4; ++sk)                                 \
                c_ = __builtin_amdgcn_mfma_f32_32x32x16_bf16(              \
                    aF[mt2][sk], BF[sk], c_, 0, 0, 0);                     \
            acc[(mh) * 2 + mt2][nh] = c_;                                  \
        }                                                                  \
    }

    // prologue: loads 1-8 = full buf0(kt=0); 9-12 = A(1)h0, B(1)h1.
    {
        __bf16* A0l = &smem[0][0][0];
        __bf16* B0l = &smem[0][1][0];
        __bf16* A1l = &smem[1][0][0];
        __bf16* B1l = &smem[1][1][0];
        STAGE_HALF(Ag, A0l, 0, 0);
        STAGE_HALF(Bg, B0l, 1, 0);
        STAGE_HALF(Ag, A0l, 1, 0);
        STAGE_HALF(Bg, B0l, 0, 0);
        STAGE_HALF(Ag, A1l, 0, 1);
        STAGE_HALF(Bg, B1l, 1, 1);
    }

    for (int kt = 0; kt < NKT; ++kt) {
        const int cur = kt & 1;
        __bf16* Ac = &smem[cur][0][0];
        __bf16* Bc = &smem[cur][1][0];
        __bf16* An = &smem[cur ^ 1][0][0];
        __bf16* Bn = &smem[cur ^ 1][1][0];

        // ---- P1: quadrant (mh=0, nh=0) ----
        FENCE();
        if (kt == NKT - 1) asm volatile("s_waitcnt vmcnt(0)" ::: "memory");
        else               asm volatile("s_waitcnt vmcnt(4)" ::: "memory");
        __builtin_amdgcn_s_barrier();
        FENCE();
        LOAD_AF(Ac, 0);
        LOAD_BF(Bc, 0, bF0);
        if (kt + 1 < NKT) {
            STAGE_HALF(Ag, An, 1, kt + 1);
            STAGE_HALF(Bg, Bn, 0, kt + 1);
        }
        asm volatile("s_waitcnt lgkmcnt(0)" ::: "memory");
        __builtin_amdgcn_sched_barrier(0);
        __builtin_amdgcn_s_setprio(1);
        MFMA_QUAD(0, 0, bF0);
        __builtin_amdgcn_s_setprio(0);

        // ---- P2: quadrant (0,1) ----
        FENCE();
        __builtin_amdgcn_s_barrier();
        FENCE();
        LOAD_BF(Bc, 1, bF1);
        asm volatile("s_waitcnt lgkmcnt(0)" ::: "memory");
        __builtin_amdgcn_sched_barrier(0);
        __builtin_amdgcn_s_setprio(1);
        MFMA_QUAD(0, 1, bF1);
        __builtin_amdgcn_s_setprio(0);

        // ---- P3: quadrant (1,1) ----
        FENCE();
        __builtin_amdgcn_s_barrier();
        FENCE();
        LOAD_AF(Ac, 1);
        if (kt + 2 < NKT) STAGE_HALF(Ag, Ac, 0, kt + 2);
        asm volatile("s_waitcnt lgkmcnt(0)" ::: "memory");
        __builtin_amdgcn_sched_barrier(0);
        __builtin_amdgcn_s_setprio(1);
        MFMA_QUAD(1, 1, bF1);
        __builtin_amdgcn_s_setprio(0);

        // ---- P4: quadrant (1,0) ----
        FENCE();
        __builtin_amdgcn_s_barrier();
        FENCE();
        if (kt + 2 < NKT) STAGE_HALF(Bg, Bc, 1, kt + 2);
        __builtin_amdgcn_s_setprio(1);
        MFMA_QUAD(1, 0, bF0);
        __builtin_amdgcn_s_setprio(0);
    }

    // epilogue: bias + store (C/D: col=lane&31, row=(r&3)+8*(r>>2)+4*(lane>>5))
    const int row0 = m0 + wm * 128 + (lane >> 5) * 4;
#pragma unroll
    for (int mt = 0; mt < 4; ++mt)
#pragma unroll
        for (int nt = 0; nt < 2; ++nt)
#pragma unroll
            for (int r = 0; r < 16; ++r) {
                const int rrow = row0 + mt * 32 + (r & 3) + 8 * (r >> 2);
                out[(size_t)rrow * D_OUT + (col0 + nt * 32)] =
                    acc[mt][nt][r] + bias_v[nt];
            }

#undef STAGE_HALF
#undef LOAD_AF
#undef LOAD_BF
#undef MFMA_QUAD
}

// ---------------------------------------------------------------------------
extern "C" void kernel_launch(void* const* d_in, const int* in_sizes, int n_in,
                              void* d_out, int out_size, void* d_ws, size_t ws_size,
                              hipStream_t stream) {
    const float* x    = (const float*)d_in[0];
    const int*   mask = (const int*)d_in[1];
    const float* W    = (const float*)d_in[2];
    const float* bias = (const float*)d_in[3];
    float*       out  = (float*)d_out;

    __bf16* wsA   = (__bf16*)((char*)d_ws + WS_A_OFF);
    __bf16* wsW   = (__bf16*)((char*)d_ws + WS_W_OFF);
    int*    s_arr = (int*)((char*)d_ws + WS_S_OFF);

    mask_sum_kernel<<<dim3(N_BATCH), dim3(256), 0, stream>>>(mask, s_arr);

    convert_kernel<<<dim3(M_DIM + D_OUT), dim3(256), 0, stream>>>(
        x, W, s_arr, wsA, wsW);

    const int grid = (M_DIM / BM) * (D_OUT / BN);  // 64 * 4 = 256
    gemm_kernel<<<dim3(grid), dim3(512), 0, stream>>>(wsA, wsW, bias, out);
}

// Round 13
// 61.605 us; speedup vs baseline: 1.1192x; 1.0534x over previous
//
#include <hip/hip_runtime.h>
#include <hip/hip_bf16.h>

// Problem constants
#define L_SEQ   4096
#define D_IN    1024
#define N_BATCH 16
#define L_OUT   1024
#define D_OUT   1024
#define M_DIM   (N_BATCH * L_OUT)   // 16384
#define K_DIM   D_IN

// GEMM tiling (256x256 8-phase template)
#define BM 256
#define BN 256
#define BK 64
#define NKT (K_DIM / BK)   // 16

typedef __attribute__((ext_vector_type(4))) float  f32x4;
typedef __attribute__((ext_vector_type(8))) __bf16 bf16x8;
typedef __attribute__((ext_vector_type(4))) __bf16 bf16x4;

// ws layout (bytes)
#define WS_A_OFF 0u
#define WS_W_OFF (32u * 1024u * 1024u)
#define WS_S_OFF (WS_W_OFF + 2u * 1024u * 1024u)

// ---------------------------------------------------------------------------
// Kernel 1: s[b] = min(sum(attention_mask[b,:]), L_OUT)
// ---------------------------------------------------------------------------
__global__ __launch_bounds__(256) void mask_sum_kernel(
    const int* __restrict__ mask, int* __restrict__ s_out)
{
    const int b = blockIdx.x;
    const int t = threadIdx.x;
    const int* row = mask + (size_t)b * L_SEQ;

    int sum = 0;
#pragma unroll
    for (int i = 0; i < L_SEQ / 256; ++i) sum += row[t + i * 256];

#pragma unroll
    for (int off = 32; off > 0; off >>= 1) sum += __shfl_down(sum, off, 64);

    __shared__ int wsum[4];
    if ((t & 63) == 0) wsum[t >> 6] = sum;
    __syncthreads();
    if (t == 0) {
        int total = wsum[0] + wsum[1] + wsum[2] + wsum[3];
        s_out[b] = total < L_OUT ? total : L_OUT;
    }
}

// ---------------------------------------------------------------------------
// Kernel 2: build bf16 A (restricted+zero-padded) and bf16 W in ws,
// pre-swizzled per row: elem e -> (e & ~63) | ((e & 63) ^ ((row&7)<<3)).
// Producer-XCD alignment: A-block cb -> row rid = (cb&7)*2048 + (cb>>3).
// ---------------------------------------------------------------------------
__global__ __launch_bounds__(256) void convert_kernel(
    const float* __restrict__ x,     // (16, 4096, 1024)
    const float* __restrict__ W,     // (1024, 1024)
    const int*   __restrict__ s_arr, // (16,)
    __bf16* __restrict__ wsA,        // (16384, 1024)
    __bf16* __restrict__ wsW)        // (1024, 1024)
{
    const int cb = blockIdx.x;
    const int t  = threadIdx.x;
    const int e0 = t * 4;

    if (cb < M_DIM) {
        const int rid = (cb & 7) * 2048 + (cb >> 3);   // XCD-aligned remap
        const int b = rid >> 10;
        const int j = rid & (L_OUT - 1);
        const int s = s_arr[b];
        const int rsw  = (rid & 7) << 3;
        const int dste = (e0 & ~63) | ((e0 & 63) ^ rsw);
        __bf16* dst = wsA + (size_t)rid * K_DIM + dste;
        if (j < s) {
            const float* src = x + ((size_t)b * L_SEQ + (L_SEQ - s + j)) * D_IN + e0;
            f32x4 v = *(const f32x4*)src;
            bf16x4 o = {(__bf16)v.x, (__bf16)v.y, (__bf16)v.z, (__bf16)v.w};
            *(bf16x4*)dst = o;
        } else {
            bf16x4 o = {(__bf16)0.f, (__bf16)0.f, (__bf16)0.f, (__bf16)0.f};
            *(bf16x4*)dst = o;
        }
    } else {
        const int n = cb - M_DIM;
        const int rsw  = (n & 7) << 3;
        const int dste = (e0 & ~63) | ((e0 & 63) ^ rsw);
        const float* src = W + (size_t)n * D_IN + e0;
        f32x4 v = *(const f32x4*)src;
        bf16x4 o = {(__bf16)v.x, (__bf16)v.y, (__bf16)v.z, (__bf16)v.w};
        *(bf16x4*)(wsW + (size_t)n * K_DIM + dste) = o;
    }
}

// ---------------------------------------------------------------------------
// Kernel 3: 256x256 GEMM, 4 barrier-phases/K-tile, counted vmcnt.
// CHANGE vs R8: the per-phase lgkmcnt(0)+sched_barrier(0) pins after ds_reads
// are REMOVED — reads are plain C++ loads, so the compiler emits fine-grained
// lgkmcnt(N) waits and interleaves reads with MFMA within each phase.
// (R10's confounded test also hoisted all reads to P1; this isolates the pin.)
// Correctness: every ds_read is consumed in its own phase (compiler-tracked);
// buffer overwrites land >=1 barrier after the last read; gload_lds counts in
// vmcnt (not lgkmcnt). vmcnt ledger unchanged:
//   at kt's P1 the 4 newest outstanding are kt-1:P3,P4 -> vmcnt(4) exact.
// ---------------------------------------------------------------------------
__device__ __forceinline__ void gload16(const __bf16* g, __bf16* l) {
    __builtin_amdgcn_global_load_lds(
        (const __attribute__((address_space(1))) void*)g,
        (__attribute__((address_space(3))) void*)l,
        16, 0, 0);
}

#define FENCE() asm volatile("" ::: "memory")

__global__ __launch_bounds__(512, 2) void gemm_kernel(
    const __bf16* __restrict__ A,    // (16384, 1024) swizzled rows
    const __bf16* __restrict__ Wb,   // (1024, 1024)  swizzled rows
    const float*  __restrict__ bias, // (1024,)
    float* __restrict__ out)         // (16384, 1024)
{
    __shared__ __bf16 smem[2][2][BM * BK];   // 128 KiB

    const int t  = threadIdx.x;       // 0..511
    const int bx = blockIdx.x;        // 256 blocks
    const int vb = (bx & 7) * 32 + (bx >> 3);  // XCD-grouping swizzle
    const int tile_n = vb & 3;        // N/BN = 4
    const int tile_m = vb >> 2;       // M/BM = 64
    const int m0 = tile_m * BM;
    const int n0 = tile_n * BN;
    const int lane = t & 63;
    const int wave = t >> 6;
    const int wm = wave >> 2;         // 0..1
    const int wn = wave & 3;          // 0..3

    const int srow = t >> 3;          // 0..63
    const int scol = (t & 7) * 8;     // linear source elem col

    const __bf16* Ag = A  + (size_t)m0 * K_DIM;
    const __bf16* Bg = Wb + (size_t)n0 * K_DIM;

#define STAGE_HALF(gbase, lbase, h, kt_)                                   \
    {                                                                      \
        _Pragma("unroll")                                                  \
        for (int rd = 0; rd < 2; ++rd) {                                   \
            const int r_ = (h) * 128 + rd * 64 + srow;                     \
            gload16((gbase) + (size_t)r_ * K_DIM + (kt_) * BK + scol,      \
                    (lbase) + r_ * BK + scol);                             \
        }                                                                  \
    }

    // fragment read geometry
    const int fr  = lane & 15;
    const int k8  = (lane >> 4) * 8;
    const int swz = (fr & 7) << 3;
    const int kc0 = k8 ^ swz;
    const int kc1 = (32 + k8) ^ swz;

    // bias hoisted ahead of the K-loop
    float bias_v[4];
#pragma unroll
    for (int g = 0; g < 4; ++g)
        bias_v[g] = bias[n0 + wn * 64 + g * 16 + fr];

    bf16x8 aF[4][2], bF0[2][2], bF1[2][2];
    f32x4 acc[8][4];
#pragma unroll
    for (int f = 0; f < 8; ++f)
#pragma unroll
        for (int g = 0; g < 4; ++g) acc[f][g] = (f32x4){0.f, 0.f, 0.f, 0.f};

#define LOAD_AF(Ac, mh)                                                    \
    {                                                                      \
        const __bf16* rb_ = (Ac) + (wm * 128 + (mh) * 64 + fr) * BK;       \
        _Pragma("unroll")                                                  \
        for (int i = 0; i < 4; ++i) {                                      \
            aF[i][0] = *(const bf16x8*)&rb_[i * 16 * BK + kc0];            \
            aF[i][1] = *(const bf16x8*)&rb_[i * 16 * BK + kc1];            \
        }                                                                  \
    }

#define LOAD_BF(Bc, nh, bF)                                                \
    {                                                                      \
        const __bf16* rb_ = (Bc) + (wn * 64 + (nh) * 32 + fr) * BK;        \
        _Pragma("unroll")                                                  \
        for (int j = 0; j < 2; ++j) {                                      \
            bF[j][0] = *(const bf16x8*)&rb_[j * 16 * BK + kc0];            \
            bF[j][1] = *(const bf16x8*)&rb_[j * 16 * BK + kc1];            \
        }                                                                  \
    }

#define MFMA_QUAD(mh, nh, bF)                                              \
    {                                                                      \
        _Pragma("unroll")                                                  \
        for (int i = 0; i < 4; ++i)                                        \
            _Pragma("unroll")                                              \
            for (int j = 0; j < 2; ++j) {                                  \
                f32x4 c_ = acc[(mh) * 4 + i][(nh) * 2 + j];                \
                c_ = __builtin_amdgcn_mfma_f32_16x16x32_bf16(              \
                    aF[i][0], bF[j][0], c_, 0, 0, 0);                      \
                c_ = __builtin_amdgcn_mfma_f32_16x16x32_bf16(              \
                    aF[i][1], bF[j][1], c_, 0, 0, 0);                      \
                acc[(mh) * 4 + i][(nh) * 2 + j] = c_;                      \
            }                                                              \
    }

    // prologue: loads 1-8 = full buf0(kt=0); 9-12 = A(1)h0, B(1)h1.
    {
        __bf16* A0l = &smem[0][0][0];
        __bf16* B0l = &smem[0][1][0];
        __bf16* A1l = &smem[1][0][0];
        __bf16* B1l = &smem[1][1][0];
        STAGE_HALF(Ag, A0l, 0, 0);
        STAGE_HALF(Bg, B0l, 1, 0);
        STAGE_HALF(Ag, A0l, 1, 0);
        STAGE_HALF(Bg, B0l, 0, 0);
        STAGE_HALF(Ag, A1l, 0, 1);
        STAGE_HALF(Bg, B1l, 1, 1);
    }

    for (int kt = 0; kt < NKT; ++kt) {
        const int cur = kt & 1;
        __bf16* Ac = &smem[cur][0][0];
        __bf16* Bc = &smem[cur][1][0];
        __bf16* An = &smem[cur ^ 1][0][0];
        __bf16* Bn = &smem[cur ^ 1][1][0];

        // ---- P1: quadrant (0,0) ----
        FENCE();
        if (kt == NKT - 1) asm volatile("s_waitcnt vmcnt(0)" ::: "memory");
        else               asm volatile("s_waitcnt vmcnt(4)" ::: "memory");
        __builtin_amdgcn_s_barrier();
        FENCE();
        LOAD_AF(Ac, 0);
        LOAD_BF(Bc, 0, bF0);
        if (kt + 1 < NKT) {
            STAGE_HALF(Ag, An, 1, kt + 1);
            STAGE_HALF(Bg, Bn, 0, kt + 1);
        }
        __builtin_amdgcn_s_setprio(1);
        MFMA_QUAD(0, 0, bF0);
        __builtin_amdgcn_s_setprio(0);

        // ---- P2: quadrant (0,1) ----
        FENCE();
        __builtin_amdgcn_s_barrier();
        FENCE();
        LOAD_BF(Bc, 1, bF1);
        __builtin_amdgcn_s_setprio(1);
        MFMA_QUAD(0, 1, bF1);
        __builtin_amdgcn_s_setprio(0);

        // ---- P3: quadrant (1,1) ----
        FENCE();
        __builtin_amdgcn_s_barrier();
        FENCE();
        LOAD_AF(Ac, 1);
        if (kt + 2 < NKT) STAGE_HALF(Ag, Ac, 0, kt + 2);
        __builtin_amdgcn_s_setprio(1);
        MFMA_QUAD(1, 1, bF1);
        __builtin_amdgcn_s_setprio(0);

        // ---- P4: quadrant (1,0) ----
        FENCE();
        __builtin_amdgcn_s_barrier();
        FENCE();
        if (kt + 2 < NKT) STAGE_HALF(Bg, Bc, 1, kt + 2);
        __builtin_amdgcn_s_setprio(1);
        MFMA_QUAD(1, 0, bF0);
        __builtin_amdgcn_s_setprio(0);
    }

    // epilogue: bias + store
    const int row0 = m0 + wm * 128 + (lane >> 4) * 4;
    const int col0 = n0 + wn * 64 + fr;
#pragma unroll
    for (int f = 0; f < 8; ++f)
#pragma unroll
        for (int g = 0; g < 4; ++g)
#pragma unroll
            for (int rr = 0; rr < 4; ++rr)
                out[(size_t)(row0 + f * 16 + rr) * D_OUT + (col0 + g * 16)] =
                    acc[f][g][rr] + bias_v[g];

#undef STAGE_HALF
#undef LOAD_AF
#undef LOAD_BF
#undef MFMA_QUAD
}

// ---------------------------------------------------------------------------
extern "C" void kernel_launch(void* const* d_in, const int* in_sizes, int n_in,
                              void* d_out, int out_size, void* d_ws, size_t ws_size,
                              hipStream_t stream) {
    const float* x    = (const float*)d_in[0];
    const int*   mask = (const int*)d_in[1];
    const float* W    = (const float*)d_in[2];
    const float* bias = (const float*)d_in[3];
    float*       out  = (float*)d_out;

    __bf16* wsA   = (__bf16*)((char*)d_ws + WS_A_OFF);
    __bf16* wsW   = (__bf16*)((char*)d_ws + WS_W_OFF);
    int*    s_arr = (int*)((char*)d_ws + WS_S_OFF);

    mask_sum_kernel<<<dim3(N_BATCH), dim3(256), 0, stream>>>(mask, s_arr);

    convert_kernel<<<dim3(M_DIM + D_OUT), dim3(256), 0, stream>>>(
        x, W, s_arr, wsA, wsW);

    const int grid = (M_DIM / BM) * (D_OUT / BN);  // 64 * 4 = 256
    gemm_kernel<<<dim3(grid), dim3(512), 0, stream>>>(wsA, wsW, bias, out);
}

// Round 16
// 55.991 us; speedup vs baseline: 1.2314x; 1.1003x over previous
//
#include <hip/hip_runtime.h>
#include <hip/hip_bf16.h>

// Problem constants
#define L_SEQ   4096
#define D_IN    1024
#define N_BATCH 16
#define L_OUT   1024
#define D_OUT   1024
#define M_DIM   (N_BATCH * L_OUT)   // 16384
#define K_DIM   D_IN

// GEMM tiling: 256x256, BK=32, fp32-A direct-from-x staging
#define BM 256
#define BN 256
#define BK 32
#define NKT (K_DIM / BK)   // 32

typedef __attribute__((ext_vector_type(4))) float  f32x4;
typedef __attribute__((ext_vector_type(8))) __bf16 bf16x8;
typedef __attribute__((ext_vector_type(4))) __bf16 bf16x4;

// ws layout (bytes): W bf16 (2 MiB) + s_arr
#define WS_W_OFF 0u
#define WS_S_OFF (4u * 1024u * 1024u)

// ---------------------------------------------------------------------------
// Kernel 1 (prep): blocks 0..15 -> mask sums; blocks 16..1039 -> W rows.
// W swizzle (32-elem groups, matches BK=32): within each 32-elem group,
// 8-elem slot sl -> sl ^ ((row>>1)&3). Read side applies the same XOR.
// ---------------------------------------------------------------------------
__global__ __launch_bounds__(256) void prep_kernel(
    const int*   __restrict__ mask,  // (16, 4096)
    const float* __restrict__ W,     // (1024, 1024)
    int*    __restrict__ s_out,      // (16,)
    __bf16* __restrict__ wsW)        // (1024, 1024) swizzled
{
    const int t = threadIdx.x;
    if (blockIdx.x < 16) {
        const int b = blockIdx.x;
        const int* row = mask + (size_t)b * L_SEQ;
        int sum = 0;
#pragma unroll
        for (int i = 0; i < L_SEQ / 256; ++i) sum += row[t + i * 256];
#pragma unroll
        for (int off = 32; off > 0; off >>= 1) sum += __shfl_down(sum, off, 64);
        __shared__ int wsum[4];
        if ((t & 63) == 0) wsum[t >> 6] = sum;
        __syncthreads();
        if (t == 0) {
            int total = wsum[0] + wsum[1] + wsum[2] + wsum[3];
            s_out[b] = total < L_OUT ? total : L_OUT;
        }
    } else {
        const int n  = blockIdx.x - 16;          // 0..1023
        const int e0 = t * 4;
        const int sl   = (e0 >> 3) & 3;
        const int dste = (e0 & ~31) | ((sl ^ ((n >> 1) & 3)) << 3) | (e0 & 7);
        const float* src = W + (size_t)n * D_IN + e0;
        f32x4 v = *(const f32x4*)src;
        bf16x4 o = {(__bf16)v.x, (__bf16)v.y, (__bf16)v.z, (__bf16)v.w};
        *(bf16x4*)(wsW + (size_t)n * K_DIM + dste) = o;
    }
}

// ---------------------------------------------------------------------------
// Kernel 2: fused GEMM, A staged fp32 DIRECTLY from x via global_load_lds.
//   out[m,n] = sum_k A[m,k]*W[n,k] + bias[n],
//   A[m,k] = (j<s_b) ? x[b, L-s_b+j, k] : 0  (cast bf16 post-ds_read).
// 256x256, BK=32, NKT=32, 8 waves (2Mx4N), 2 phases/kt (16 MFMA each).
// LDS 128 KiB: sAf fp32 TRIPLE-buffered 3x32KB (R15 race fix), sB bf16 2x16KB.
// A content XOR-swizzled via per-lane SOURCE addr, linear dest (m173);
// B ws-pre-swizzled, linear staging.
// WRITE-SAFETY (the R15 bug): every stage target is >=1 barrier past its
// last reader. A(kt+2) -> a2 (= buffer of A(kt-1), last read P2(kt-1),
// barrier at P1(kt) separates). B(kt+1) -> sB[nxt] (last read P1(kt-1),
// barriers at P2(kt-1) and P1(kt) separate). No same-phase overwrite.
// vmcnt ledger (in-order queue, derived):
//   prologue A(0)4, B(0)2, A(1)4 -> P1(0): vmcnt(4) retires A(0)+B(0).
//   steady: P1(kt) issues B(kt+1)2; P2(kt) issues A(kt+2)4;
//   at P1(kt): outstanding [B(kt)2][A(kt+1)4] -> vmcnt(4) retires B(kt)
//   (and older A(kt)), leaves A(kt+1). Last kt: vmcnt(0).
// Masked rows: clamped-safe addr; block-uniform cold path zeroes a0 rows
// j>=s after the barrier, before reads (hot path s==1024: 1 scc branch/kt).
// ---------------------------------------------------------------------------
__device__ __forceinline__ void gload16v(const void* g, void* l) {
    __builtin_amdgcn_global_load_lds(
        (const __attribute__((address_space(1))) void*)g,
        (__attribute__((address_space(3))) void*)l,
        16, 0, 0);
}

#define FENCE() asm volatile("" ::: "memory")

__global__ __launch_bounds__(512, 2) void gemm_kernel(
    const float*  __restrict__ x,    // (16, 4096, 1024) fp32
    const __bf16* __restrict__ Wb,   // (1024, 1024) swizzled bf16
    const float*  __restrict__ bias, // (1024,)
    const int*    __restrict__ s_arr,// (16,)
    float* __restrict__ out)         // (16384, 1024)
{
    __shared__ float  sAf[3][BM * BK];   // 96 KiB (fp32 A, triple buffer)
    __shared__ __bf16 sB [2][BN * BK];   // 32 KiB (bf16 B, double buffer)

    const int t  = threadIdx.x;       // 0..511
    const int bx = blockIdx.x;        // 256 blocks
    const int vb = (bx & 7) * 32 + (bx >> 3);  // T1 XCD-grouping swizzle
    const int tile_n = vb & 3;
    const int tile_m = vb >> 2;
    const int m0 = tile_m * BM;
    const int n0 = tile_n * BN;
    const int lane = t & 63;
    const int wave = t >> 6;
    const int wm = wave >> 2;         // 0..1
    const int wn = wave & 3;          // 0..3

    // ---- A staging geometry (4 rounds x 64 rows x 32 f32) ----
    const int bb = m0 >> 10;
    const int s  = s_arr[bb];
    const int jb = m0 & (L_OUT - 1);
    const float* xb = x + (size_t)bb * L_SEQ * D_IN;
    // per-lane swizzled SOURCE col (f32 elems): slot(t&7) ^ row(t>>3)&7
    const int ascol = (((t & 7) ^ ((t >> 3) & 7)) * 4);
    const float* asrc[4];
    int  adst[4];
    int  arow[4];
#pragma unroll
    for (int r = 0; r < 4; ++r) {
        const int rr = 64 * r + (t >> 3);        // row in tile 0..255
        const int j  = jb + rr;
        const int xr = (j < s) ? (L_SEQ - s + j) : 0;  // clamped-safe
        asrc[r] = xb + (size_t)xr * D_IN + ascol;
        adst[r] = rr * BK + (t & 7) * 4;         // linear dest (f32 elems)
        arow[r] = j;
    }
#define STAGE_A(abuf, kt_)                                                 \
    {                                                                      \
        _Pragma("unroll")                                                  \
        for (int r = 0; r < 4; ++r)                                        \
            gload16v(asrc[r] + (kt_) * BK, (abuf) + adst[r]);              \
    }

    // ---- B staging geometry (2 rounds x 128 rows x 32 bf16) ----
    const __bf16* Bg = Wb + (size_t)n0 * K_DIM;
    const int brow = t >> 2;          // 0..127
    const int bcol = (t & 3) * 8;     // elem col (linear; content swizzled)
#define STAGE_B(buf, kt_)                                                  \
    {                                                                      \
        _Pragma("unroll")                                                  \
        for (int r = 0; r < 2; ++r) {                                      \
            const int row_ = 128 * r + brow;                               \
            gload16v(Bg + (size_t)row_ * K_DIM + (kt_) * BK + bcol,        \
                     &sB[buf][row_ * BK + bcol]);                          \
        }                                                                  \
    }

    // ---- fragment read geometry ----
    const int fr = lane & 15;
    const int g4 = lane >> 4;         // 0..3 (k-group)

    float bias_v[4];
#pragma unroll
    for (int gg = 0; gg < 4; ++gg)
        bias_v[gg] = bias[n0 + wn * 64 + gg * 16 + fr];

    bf16x8 aF[4], bB0[2], bB1[2];
    f32x4 acc[8][4];
#pragma unroll
    for (int f = 0; f < 8; ++f)
#pragma unroll
        for (int gg = 0; gg < 4; ++gg) acc[f][gg] = (f32x4){0.f, 0.f, 0.f, 0.f};

    // A frag: R = wm*128 + mh*64 + i*16 + fr; slots (2g4, 2g4+1) ^ (R&7)
#define LOAD_A32(abuf, mh)                                                 \
    {                                                                      \
        _Pragma("unroll")                                                  \
        for (int i = 0; i < 4; ++i) {                                      \
            const int R_ = wm * 128 + (mh) * 64 + i * 16 + fr;             \
            const float* rbase_ = (abuf) + R_ * BK;                        \
            f32x4 lo_ = *(const f32x4*)&rbase_[((2*g4)   ^ (R_ & 7)) * 4]; \
            f32x4 hi_ = *(const f32x4*)&rbase_[((2*g4+1) ^ (R_ & 7)) * 4]; \
            aF[i] = (bf16x8){(__bf16)lo_.x, (__bf16)lo_.y, (__bf16)lo_.z,  \
                             (__bf16)lo_.w, (__bf16)hi_.x, (__bf16)hi_.y,  \
                             (__bf16)hi_.z, (__bf16)hi_.w};                \
        }                                                                  \
    }

    // B frag: RB = wn*64 + nh*32 + j*16 + fr; slot g4 ^ ((RB>>1)&3)
#define LOAD_B(buf, nh, BB)                                                \
    {                                                                      \
        _Pragma("unroll")                                                  \
        for (int j = 0; j < 2; ++j) {                                      \
            const int RB_ = wn * 64 + (nh) * 32 + j * 16 + fr;             \
            BB[j] = *(const bf16x8*)                                       \
                &sB[buf][RB_ * BK + (g4 ^ ((RB_ >> 1) & 3)) * 8];          \
        }                                                                  \
    }

#define MFMA8(mh, nh, BB)                                                  \
    {                                                                      \
        _Pragma("unroll")                                                  \
        for (int i = 0; i < 4; ++i)                                        \
            _Pragma("unroll")                                              \
            for (int j = 0; j < 2; ++j)                                    \
                acc[(mh) * 4 + i][(nh) * 2 + j] =                          \
                    __builtin_amdgcn_mfma_f32_16x16x32_bf16(               \
                        aF[i], BB[j], acc[(mh) * 4 + i][(nh) * 2 + j],     \
                        0, 0, 0);                                          \
    }

    // rotating A buffers: a0 = A(kt), a1 = A(kt+1), a2 = stage target A(kt+2)
    float* a0 = &sAf[0][0];
    float* a1 = &sAf[1][0];
    float* a2 = &sAf[2][0];

    // ---- prologue: A(0)[4], B(0)[2], A(1)[4] -> 10 outstanding ----
    STAGE_A(a0, 0);
    STAGE_B(0, 0);
    STAGE_A(a1, 1);

    for (int kt = 0; kt < NKT; ++kt) {
        const int cur = kt & 1;
        const int nxt = cur ^ 1;

        // ---- P1: mh=0, both nh ----
        FENCE();
        if (kt == NKT - 1) asm volatile("s_waitcnt vmcnt(0)" ::: "memory");
        else               asm volatile("s_waitcnt vmcnt(4)" ::: "memory");
        __builtin_amdgcn_s_barrier();
        FENCE();
        if (s < L_OUT) {        // cold path: zero masked rows (block-uniform)
#pragma unroll
            for (int r = 0; r < 4; ++r)
                if (arow[r] >= s)
                    *(f32x4*)&a0[adst[r]] = (f32x4){0.f, 0.f, 0.f, 0.f};
            __syncthreads();
        }
        LOAD_A32(a0, 0);
        LOAD_B(cur, 0, bB0);
        LOAD_B(cur, 1, bB1);
        if (kt + 1 < NKT) STAGE_B(nxt, kt + 1);
        __builtin_amdgcn_s_setprio(1);
        MFMA8(0, 0, bB0);
        MFMA8(0, 1, bB1);
        __builtin_amdgcn_s_setprio(0);

        // ---- P2: mh=1, both nh ----
        FENCE();
        __builtin_amdgcn_s_barrier();
        FENCE();
        LOAD_A32(a0, 1);
        if (kt + 2 < NKT) STAGE_A(a2, kt + 2);   // a2 last read at P2(kt-1)
        __builtin_amdgcn_s_setprio(1);
        MFMA8(1, 1, bB1);
        MFMA8(1, 0, bB0);
        __builtin_amdgcn_s_setprio(0);

        // rotate A buffers
        float* ta = a0; a0 = a1; a1 = a2; a2 = ta;
    }

    // ---- epilogue: bias + store ----
    const int row0 = m0 + wm * 128 + (lane >> 4) * 4;
    const int col0 = n0 + wn * 64 + fr;
#pragma unroll
    for (int f = 0; f < 8; ++f)
#pragma unroll
        for (int gg = 0; gg < 4; ++gg)
#pragma unroll
            for (int rr = 0; rr < 4; ++rr)
                out[(size_t)(row0 + f * 16 + rr) * D_OUT + (col0 + gg * 16)] =
                    acc[f][gg][rr] + bias_v[gg];

#undef STAGE_A
#undef STAGE_B
#undef LOAD_A32
#undef LOAD_B
#undef MFMA8
}

// ---------------------------------------------------------------------------
extern "C" void kernel_launch(void* const* d_in, const int* in_sizes, int n_in,
                              void* d_out, int out_size, void* d_ws, size_t ws_size,
                              hipStream_t stream) {
    const float* x    = (const float*)d_in[0];
    const int*   mask = (const int*)d_in[1];
    const float* W    = (const float*)d_in[2];
    const float* bias = (const float*)d_in[3];
    float*       out  = (float*)d_out;

    __bf16* wsW   = (__bf16*)((char*)d_ws + WS_W_OFF);
    int*    s_arr = (int*)((char*)d_ws + WS_S_OFF);

    prep_kernel<<<dim3(16 + D_OUT), dim3(256), 0, stream>>>(
        mask, W, s_arr, wsW);

    const int grid = (M_DIM / BM) * (D_OUT / BN);  // 64 * 4 = 256
    gemm_kernel<<<dim3(grid), dim3(512), 0, stream>>>(
        x, wsW, bias, s_arr, out);
}

// Round 17
// 51.792 us; speedup vs baseline: 1.3312x; 1.0811x over previous
//
#include <hip/hip_runtime.h>
#include <hip/hip_bf16.h>

// Problem constants
#define L_SEQ   4096
#define D_IN    1024
#define N_BATCH 16
#define L_OUT   1024
#define D_OUT   1024
#define M_DIM   (N_BATCH * L_OUT)   // 16384
#define K_DIM   D_IN

// GEMM tiling: 256x256, BK=32, fp32-A direct-from-x staging
#define BM 256
#define BN 256
#define BK 32
#define NKT (K_DIM / BK)   // 32

typedef __attribute__((ext_vector_type(4))) float  f32x4;
typedef __attribute__((ext_vector_type(8))) __bf16 bf16x8;
typedef __attribute__((ext_vector_type(4))) __bf16 bf16x4;

// ws layout (bytes): W bf16 (2 MiB) + s_arr
#define WS_W_OFF 0u
#define WS_S_OFF (4u * 1024u * 1024u)

// ---------------------------------------------------------------------------
// Kernel 1 (prep): blocks 0..15 -> mask sums; blocks 16..1039 -> W rows.
// W swizzle (32-elem groups): 8-elem slot sl -> sl ^ ((row>>1)&3).
// ---------------------------------------------------------------------------
__global__ __launch_bounds__(256) void prep_kernel(
    const int*   __restrict__ mask,  // (16, 4096)
    const float* __restrict__ W,     // (1024, 1024)
    int*    __restrict__ s_out,      // (16,)
    __bf16* __restrict__ wsW)        // (1024, 1024) swizzled
{
    const int t = threadIdx.x;
    if (blockIdx.x < 16) {
        const int b = blockIdx.x;
        const int* row = mask + (size_t)b * L_SEQ;
        int sum = 0;
#pragma unroll
        for (int i = 0; i < L_SEQ / 256; ++i) sum += row[t + i * 256];
#pragma unroll
        for (int off = 32; off > 0; off >>= 1) sum += __shfl_down(sum, off, 64);
        __shared__ int wsum[4];
        if ((t & 63) == 0) wsum[t >> 6] = sum;
        __syncthreads();
        if (t == 0) {
            int total = wsum[0] + wsum[1] + wsum[2] + wsum[3];
            s_out[b] = total < L_OUT ? total : L_OUT;
        }
    } else {
        const int n  = blockIdx.x - 16;          // 0..1023
        const int e0 = t * 4;
        const int sl   = (e0 >> 3) & 3;
        const int dste = (e0 & ~31) | ((sl ^ ((n >> 1) & 3)) << 3) | (e0 & 7);
        const float* src = W + (size_t)n * D_IN + e0;
        f32x4 v = *(const f32x4*)src;
        bf16x4 o = {(__bf16)v.x, (__bf16)v.y, (__bf16)v.z, (__bf16)v.w};
        *(bf16x4*)(wsW + (size_t)n * K_DIM + dste) = o;
    }
}

// ---------------------------------------------------------------------------
// Kernel 2: fused GEMM, A staged fp32 DIRECTLY from x via global_load_lds.
// CHANGE vs R16: wave grid 2Mx4N -> 4Mx2N (wave tile 64x128).
//   A-fragment reads halved (each A row read by 2 waves, not 4):
//   per wave per kt: A 8 b128 + B 8 b128 = 16 (was 20) -> LDS traffic -27%
//   (the diagnosed bottleneck: 208 KB/kt ~ 1630 cyc vs MFMA 1230 cyc).
// acc[4][8] f32x4 = 128 VGPR (unchanged). Phases: P1 = A-frags + B q0-3 +
// 16 MFMA; P2 = B q4-7 + 16 MFMA. Staging schedule/ledger identical to R16:
//   prologue A(0)4, B(0)2, A(1)4; P1(kt) stages B(kt+1)2; P2(kt) A(kt+2)4;
//   P1(kt) waits vmcnt(4) (retires A(kt)+B(kt), leaves A(kt+1)); last kt 0.
// WRITE-SAFETY: A(kt+2)->a2 (last read P1(kt-1), 2 barriers back);
// B(kt+2)->cur(kt)'s buffer at P1(kt+1), after P2(kt) reads retired at the
// P1(kt+1) barrier. No same-phase overwrite of a read set (R15 lesson).
// ---------------------------------------------------------------------------
__device__ __forceinline__ void gload16v(const void* g, void* l) {
    __builtin_amdgcn_global_load_lds(
        (const __attribute__((address_space(1))) void*)g,
        (__attribute__((address_space(3))) void*)l,
        16, 0, 0);
}

#define FENCE() asm volatile("" ::: "memory")

__global__ __launch_bounds__(512, 2) void gemm_kernel(
    const float*  __restrict__ x,    // (16, 4096, 1024) fp32
    const __bf16* __restrict__ Wb,   // (1024, 1024) swizzled bf16
    const float*  __restrict__ bias, // (1024,)
    const int*    __restrict__ s_arr,// (16,)
    float* __restrict__ out)         // (16384, 1024)
{
    __shared__ float  sAf[3][BM * BK];   // 96 KiB (fp32 A, triple buffer)
    __shared__ __bf16 sB [2][BN * BK];   // 32 KiB (bf16 B, double buffer)

    const int t  = threadIdx.x;       // 0..511
    const int bx = blockIdx.x;        // 256 blocks
    const int vb = (bx & 7) * 32 + (bx >> 3);  // T1 XCD-grouping swizzle
    const int tile_n = vb & 3;
    const int tile_m = vb >> 2;
    const int m0 = tile_m * BM;
    const int n0 = tile_n * BN;
    const int lane = t & 63;
    const int wave = t >> 6;
    const int wm = wave & 3;          // 0..3 (64 rows each)
    const int wn = wave >> 2;         // 0..1 (128 cols each)

    // ---- A staging geometry (4 rounds x 64 rows x 32 f32) ----
    const int bb = m0 >> 10;
    const int s  = s_arr[bb];
    const int jb = m0 & (L_OUT - 1);
    const float* xb = x + (size_t)bb * L_SEQ * D_IN;
    const int ascol = (((t & 7) ^ ((t >> 3) & 7)) * 4);   // swizzled SOURCE col
    const float* asrc[4];
    int  adst[4];
    int  arow[4];
#pragma unroll
    for (int r = 0; r < 4; ++r) {
        const int rr = 64 * r + (t >> 3);        // row in tile 0..255
        const int j  = jb + rr;
        const int xr = (j < s) ? (L_SEQ - s + j) : 0;  // clamped-safe
        asrc[r] = xb + (size_t)xr * D_IN + ascol;
        adst[r] = rr * BK + (t & 7) * 4;         // linear dest (f32 elems)
        arow[r] = j;
    }
#define STAGE_A(abuf, kt_)                                                 \
    {                                                                      \
        _Pragma("unroll")                                                  \
        for (int r = 0; r < 4; ++r)                                        \
            gload16v(asrc[r] + (kt_) * BK, (abuf) + adst[r]);              \
    }

    // ---- B staging geometry (2 rounds x 128 rows x 32 bf16) ----
    const __bf16* Bg = Wb + (size_t)n0 * K_DIM;
    const int brow = t >> 2;          // 0..127
    const int bcol = (t & 3) * 8;     // elem col (linear; content swizzled)
#define STAGE_B(buf, kt_)                                                  \
    {                                                                      \
        _Pragma("unroll")                                                  \
        for (int r = 0; r < 2; ++r) {                                      \
            const int row_ = 128 * r + brow;                               \
            gload16v(Bg + (size_t)row_ * K_DIM + (kt_) * BK + bcol,        \
                     &sB[buf][row_ * BK + bcol]);                          \
        }                                                                  \
    }

    // ---- fragment read geometry ----
    const int fr = lane & 15;
    const int g4 = lane >> 4;         // 0..3 (k-group)

    float bias_v[8];
#pragma unroll
    for (int q = 0; q < 8; ++q)
        bias_v[q] = bias[n0 + wn * 128 + q * 16 + fr];

    bf16x8 aF[4], bBlo[4], bBhi[4];
    f32x4 acc[4][8];
#pragma unroll
    for (int i = 0; i < 4; ++i)
#pragma unroll
        for (int q = 0; q < 8; ++q) acc[i][q] = (f32x4){0.f, 0.f, 0.f, 0.f};

    // A frag: R = wm*64 + i*16 + fr; slots (2g4, 2g4+1) ^ (R&7)
#define LOAD_A32(abuf)                                                     \
    {                                                                      \
        _Pragma("unroll")                                                  \
        for (int i = 0; i < 4; ++i) {                                      \
            const int R_ = wm * 64 + i * 16 + fr;                          \
            const float* rbase_ = (abuf) + R_ * BK;                        \
            f32x4 lo_ = *(const f32x4*)&rbase_[((2*g4)   ^ (R_ & 7)) * 4]; \
            f32x4 hi_ = *(const f32x4*)&rbase_[((2*g4+1) ^ (R_ & 7)) * 4]; \
            aF[i] = (bf16x8){(__bf16)lo_.x, (__bf16)lo_.y, (__bf16)lo_.z,  \
                             (__bf16)lo_.w, (__bf16)hi_.x, (__bf16)hi_.y,  \
                             (__bf16)hi_.z, (__bf16)hi_.w};                \
        }                                                                  \
    }

    // B frag: RB = wn*128 + (qb+j)*16 + fr; slot g4 ^ ((RB>>1)&3)
#define LOAD_B4(buf, qb, BB)                                               \
    {                                                                      \
        _Pragma("unroll")                                                  \
        for (int j = 0; j < 4; ++j) {                                      \
            const int RB_ = wn * 128 + ((qb) + j) * 16 + fr;               \
            BB[j] = *(const bf16x8*)                                       \
                &sB[buf][RB_ * BK + (g4 ^ ((RB_ >> 1) & 3)) * 8];          \
        }                                                                  \
    }

#define MFMA16(qb, BB)                                                     \
    {                                                                      \
        _Pragma("unroll")                                                  \
        for (int i = 0; i < 4; ++i)                                        \
            _Pragma("unroll")                                              \
            for (int j = 0; j < 4; ++j)                                    \
                acc[i][(qb) + j] =                                         \
                    __builtin_amdgcn_mfma_f32_16x16x32_bf16(               \
                        aF[i], BB[j], acc[i][(qb) + j], 0, 0, 0);          \
    }

    // rotating A buffers: a0 = A(kt), a1 = A(kt+1), a2 = stage target A(kt+2)
    float* a0 = &sAf[0][0];
    float* a1 = &sAf[1][0];
    float* a2 = &sAf[2][0];

    // ---- prologue: A(0)[4], B(0)[2], A(1)[4] ----
    STAGE_A(a0, 0);
    STAGE_B(0, 0);
    STAGE_A(a1, 1);

    for (int kt = 0; kt < NKT; ++kt) {
        const int cur = kt & 1;
        const int nxt = cur ^ 1;

        // ---- P1: A-frags + B q0-3, MFMA qb=0 ----
        FENCE();
        if (kt == NKT - 1) asm volatile("s_waitcnt vmcnt(0)" ::: "memory");
        else               asm volatile("s_waitcnt vmcnt(4)" ::: "memory");
        __builtin_amdgcn_s_barrier();
        FENCE();
        if (s < L_OUT) {        // cold path: zero masked rows (block-uniform)
#pragma unroll
            for (int r = 0; r < 4; ++r)
                if (arow[r] >= s)
                    *(f32x4*)&a0[adst[r]] = (f32x4){0.f, 0.f, 0.f, 0.f};
            __syncthreads();
        }
        LOAD_A32(a0);
        LOAD_B4(cur, 0, bBlo);
        if (kt + 1 < NKT) STAGE_B(nxt, kt + 1);
        __builtin_amdgcn_s_setprio(1);
        MFMA16(0, bBlo);
        __builtin_amdgcn_s_setprio(0);

        // ---- P2: B q4-7, MFMA qb=4 ----
        FENCE();
        __builtin_amdgcn_s_barrier();
        FENCE();
        LOAD_B4(cur, 4, bBhi);
        if (kt + 2 < NKT) STAGE_A(a2, kt + 2);   // a2 last read P1(kt-1)
        __builtin_amdgcn_s_setprio(1);
        MFMA16(4, bBhi);
        __builtin_amdgcn_s_setprio(0);

        // rotate A buffers
        float* ta = a0; a0 = a1; a1 = a2; a2 = ta;
    }

    // ---- epilogue: bias + store ----
    const int row0 = m0 + wm * 64 + (lane >> 4) * 4;
    const int col0 = n0 + wn * 128 + fr;
#pragma unroll
    for (int i = 0; i < 4; ++i)
#pragma unroll
        for (int q = 0; q < 8; ++q)
#pragma unroll
            for (int rr = 0; rr < 4; ++rr)
                out[(size_t)(row0 + i * 16 + rr) * D_OUT + (col0 + q * 16)] =
                    acc[i][q][rr] + bias_v[q];

#undef STAGE_A
#undef STAGE_B
#undef LOAD_A32
#undef LOAD_B4
#undef MFMA16
}

// ---------------------------------------------------------------------------
extern "C" void kernel_launch(void* const* d_in, const int* in_sizes, int n_in,
                              void* d_out, int out_size, void* d_ws, size_t ws_size,
                              hipStream_t stream) {
    const float* x    = (const float*)d_in[0];
    const int*   mask = (const int*)d_in[1];
    const float* W    = (const float*)d_in[2];
    const float* bias = (const float*)d_in[3];
    float*       out  = (float*)d_out;

    __bf16* wsW   = (__bf16*)((char*)d_ws + WS_W_OFF);
    int*    s_arr = (int*)((char*)d_ws + WS_S_OFF);

    prep_kernel<<<dim3(16 + D_OUT), dim3(256), 0, stream>>>(
        mask, W, s_arr, wsW);

    const int grid = (M_DIM / BM) * (D_OUT / BN);  // 64 * 4 = 256
    gemm_kernel<<<dim3(grid), dim3(512), 0, stream>>>(
        x, wsW, bias, s_arr, out);
}